// Round 11
// baseline (1378.417 us; speedup 1.0000x reference)
//
#include <hip/hip_runtime.h>
#include <hip/hip_bf16.h>
#include <math.h>

typedef unsigned short ushort_t;
typedef unsigned int uint_t;

// Problem constants: S=32 scenes, N=32 peds, B=1024, E=64, H=128, PRE=512, MLP_D=1024, T=12
// All float inputs are f32; output is f32.
#define T_ 12

// ---- ws layout (float offsets) ----
#define F_LP0   0         // last_pos      (2048)
#define F_LPR   2048      // last_pos_rel  (2048)
#define F_H0    4096      // h0            (131072)
#define F_C0    135168    // c0            (131072)
#define F_WSP   266240    // Wsp (64,2)
#define F_BSP   266368    // bsp (64)
#define F_WIH   266432    // Wih (512,64)
#define F_WHH   299200    // Whh (512,128)
#define F_BIH   364736
#define F_BHH   365248
#define F_WH2P  365760    // (2,128)
#define F_BH2P  366016    // (2)
#define F_WPE   366032    // (64,2)
#define F_BPE   366160    // (64)
#define F_WP1   366224    // (512,192)
#define F_BP1   464528    // (512)
#define F_WP2   465040    // (128,512)
#define F_BP2   530576    // (128)
#define F_WM1   530704    // (1024,256)
#define F_BM1   792848    // (1024)
#define F_WM2   793872    // (128,1024)
#define F_BM2   924944    // (128)
// State / derived:
#define OFF_HC   925072   // initial hidden (B,128)  [prologue read only]
#define OFF_LPB  1056144  // LP parity-1 (B,2)       [freed HL slot]
#define OFF_C    1187216  // initial cell (B,128)    [prologue read only]
#define OFF_X    1318288  // initial lstm input (B,64) [prologue read only]
#define OFF_LP   1383824  // LP parity-0 (B,2)
#define OFF_HP   1385872  // HP bf16 ping-pong: 2 x (1024x512) ushorts = 524288 floats
#define OFF_A2   1910160  // (2,512)
#define OFF_B512 1911184  // (512)
#define OFF_W2F  1911696  // Wp2 bf16 B-frag pack (65536 ushorts)
#define OFF_PHP  1977232  // pool max output (B,128)
#define OFF_HPF  2108304  // Wp1b B-frag pack (65536 ushorts)
#define OFF_M1F  2141072  // Wm1 B-frag pack (262144 ushorts)
#define OFF_M2F  2272144  // Wm2 B-frag pack (131072 ushorts)
#define OFF_BG   2337680  // gate bias bih+bhh (512)
#define OFF_LF   2338192  // Wih|Whh B-frag pack (98304 ushorts = 49152 floats)
#define OFF_BAR  2387344  // per-scene barrier: cnt[s] @ +s*16, gen[s] @ +512+s*16 (1024 uints)
// total ~2387600 floats = ~9.55 MB of d_ws

typedef __attribute__((ext_vector_type(8))) short short8v;   // 8 bf16 (4 VGPRs)
typedef __attribute__((ext_vector_type(4))) float f32x4;

__device__ __forceinline__ float sigf(float x){ return 1.0f/(1.0f+expf(-x)); }
__device__ __forceinline__ uint_t f2b(float f){  // RNE f32->bf16 (bits in low 16)
    uint_t u = __float_as_uint(f);
    return (u + 0x7FFFu + ((u >> 16) & 1u)) >> 16;
}
__device__ __forceinline__ float blo(uint_t u){ union{uint_t i; float f;} v; v.i=u<<16; return v.f; }
__device__ __forceinline__ float bhi(uint_t u){ union{uint_t i; float f;} v; v.i=u&0xffff0000u; return v.f; }

struct Ptrs { const void* p[22]; };

// ---- 8-block group barrier (per scene). cnt & gen lines 2KB apart; relaxed poll,
// one acquire at exit; release via store. 32 groups run independently.
__device__ __forceinline__ void group_barrier(uint_t* cnt, uint_t* gen)
{
    __syncthreads();
    if (threadIdx.x == 0) {
        uint_t g = __hip_atomic_load(gen, __ATOMIC_RELAXED, __HIP_MEMORY_SCOPE_AGENT);
        if (__hip_atomic_fetch_add(cnt, 1u, __ATOMIC_ACQ_REL, __HIP_MEMORY_SCOPE_AGENT) == 7u) {
            __hip_atomic_store(cnt, 0u, __ATOMIC_RELAXED, __HIP_MEMORY_SCOPE_AGENT);
            __hip_atomic_store(gen, g + 1u, __ATOMIC_RELEASE, __HIP_MEMORY_SCOPE_AGENT);
        } else {
            while (__hip_atomic_load(gen, __ATOMIC_RELAXED, __HIP_MEMORY_SCOPE_AGENT) == g)
                __builtin_amdgcn_s_sleep(4);
            (void)__hip_atomic_load(gen, __ATOMIC_ACQUIRE, __HIP_MEMORY_SCOPE_AGENT);
        }
    }
    __syncthreads();
}

// ---------------- copy all f32 inputs into consolidated ws region ----------------
__global__ __launch_bounds__(256) void k_conv(Ptrs ptrs, float* __restrict__ ws)
{
    const int cums[22] = {0,2048,4096,135168,266240,266368,266432,299200,364736,
                          365248,365760,366016,366018,366146,366210,464514,465026,
                          530562,530690,792834,793858,924930};
    const int dof[22]  = {F_LP0,F_LPR,F_H0,F_C0,F_WSP,F_BSP,F_WIH,F_WHH,F_BIH,F_BHH,
                          F_WH2P,F_BH2P,F_WPE,F_BPE,F_WP1,F_BP1,F_WP2,F_BP2,F_WM1,
                          F_BM1,F_WM2,F_BM2};
    const int TOTAL = 925058;
    int g = blockIdx.x*256 + threadIdx.x;
    if (g < TOTAL) {
        int t = 0;
        #pragma unroll
        for (int i = 1; i < 22; i++) t += (g >= cums[i]);
        int li = g - cums[t];
        ws[dof[t] + li] = ((const float*)ptrs.p[t])[li];
    }
}

// ---------------- init: h,c copy; x0; lp parity-0; zero barrier lines ----------------
__global__ __launch_bounds__(128) void k_init(float* __restrict__ ws)
{
    const int b = blockIdx.x, tid = threadIdx.x;
    ws[OFF_HC + b*128 + tid] = ws[F_H0 + b*128 + tid];
    ws[OFF_C  + b*128 + tid] = ws[F_C0 + b*128 + tid];
    if (tid < 64) {
        float p0 = ws[F_LPR + b*2], p1 = ws[F_LPR + b*2 + 1];
        ws[OFF_X + b*64 + tid] = p0*ws[F_WSP + tid*2] + p1*ws[F_WSP + tid*2+1] + ws[F_BSP + tid];
    }
    if (tid < 2) ws[OFF_LP + b*2 + tid] = ws[F_LP0 + b*2 + tid];
    if (b < 8) ((uint_t*)(ws + OFF_BAR))[b*128 + tid] = 0u;   // re-zero barrier each call
}

// ---------------- A2/B512 + gate bias ----------------
__global__ __launch_bounds__(256) void k_pre2(float* __restrict__ ws)
{
    const int k = blockIdx.x*256 + threadIdx.x;   // 0..511
    float a0 = 0.f, a1 = 0.f, bb = 0.f;
    for (int e = 0; e < 64; e++) {
        float w = ws[F_WP1 + k*192 + e];
        a0 += ws[F_WPE + e*2 + 0] * w;
        a1 += ws[F_WPE + e*2 + 1] * w;
        bb += ws[F_BPE + e]       * w;
    }
    ws[OFF_A2 + k]       = a0;
    ws[OFF_A2 + 512 + k] = a1;
    ws[OFF_B512 + k]     = bb + ws[F_BP1 + k];
    ws[OFF_BG + k]       = ws[F_BIH + k] + ws[F_BHH + k];
}

// ---------------- merged B-frag packs: W2F, HPF, M1F, M2F, LF ----------------
__global__ __launch_bounds__(256) void k_packs(float* __restrict__ ws)
{
    const int g = blockIdx.x*256 + threadIdx.x;
    if (g >= 622592) return;
    const int cums[6] = {0,65536,131072,393216,524288,622592};
    int rgn = 0;
    #pragma unroll
    for (int i = 1; i < 5; i++) rgn += (g >= cums[i]);
    const int li = g - cums[rgn];
    const int Ks[5]   = {512, 128, 256, 1024, 192};
    const int src[5]  = {F_WP2, F_WP1, F_WM1, F_WM2, 0};
    const int strd[5] = {512, 192, 256, 1024, 0};
    const int coff[5] = {0, 64, 0, 0, 0};
    const int dst[5]  = {OFF_W2F, OFF_HPF, OFF_M1F, OFF_M2F, OFF_LF};
    const int K = Ks[rgn];
    const int i = li & 7, lane = (li >> 3) & 63, rest = li >> 9;
    const int nkk = K >> 5, kk = rest % nkk, nt = rest / nkk;
    const int n = nt*16 + (lane & 15);
    const int k = kk*32 + ((lane >> 4) << 3) + i;
    float v;
    if (rgn == 4) v = (k < 64) ? ws[F_WIH + n*64 + k] : ws[F_WHH + n*128 + (k - 64)];
    else          v = ws[src[rgn] + n*strd[rgn] + coff[rgn] + k];
    ((ushort_t*)(ws + dst[rgn]))[li] = (ushort_t)f2b(v);
}

// ---------------- persistent scene-group kernel ----------------
// Block = 8s+m: scene s (32 groups of 8), member m owns rows r0=s*32+m*4 .. +3.
// Per step: L{gates+pointwise+h2p+X+hp, member-local} -> GROUP BARRIER ->
// P{pool 4 i's, reads scene HP/LP} -> M{mlp 4 rows, member-local} -> next step.
// HP & LP ping-pong buffers break WAR races across the single barrier.
__global__ __launch_bounds__(256, 1) void k_run(float* __restrict__ ws, float* __restrict__ out)
{
    __shared__ __align__(16) char smem[43520];
    const int tid = threadIdx.x;
    const int bid = blockIdx.x;
    const int s = bid >> 3, m = bid & 7;
    const int r0 = s*32 + m*4;
    uint_t* barp = (uint_t*)(ws + OFF_BAR);
    uint_t* cnt = barp + s*16;
    uint_t* gen = barp + 512 + s*16;

    const int lane = tid & 63, w = tid >> 6;
    const int arow = lane & 15, kch = (lane >> 4) * 8;

    // persistent per-thread state (x: row tid>>6, col tid&63; c,h: rows 2*(tid>>7)+j, col tid&127)
    float x_reg = ws[OFF_X + (r0 + (tid >> 6))*64 + (tid & 63)];
    float c_reg[2], h_reg[2];
    #pragma unroll
    for (int j = 0; j < 2; j++) {
        const int r = 2*(tid >> 7) + j;
        c_reg[j] = ws[OFF_C  + (r0 + r)*128 + (tid & 127)];
        h_reg[j] = ws[OFF_HC + (r0 + r)*128 + (tid & 127)];
    }
    const float wsp0 = ws[F_WSP + (tid & 63)*2];
    const float wsp1 = ws[F_WSP + (tid & 63)*2 + 1];
    const float bsp  = ws[F_BSP + (tid & 63)];

    const ushort_t* LF  = (const ushort_t*)(ws + OFF_LF);
    const ushort_t* HPF = (const ushort_t*)(ws + OFF_HPF);
    const ushort_t* W2F = (const ushort_t*)(ws + OFF_W2F);
    const ushort_t* M1F = (const ushort_t*)(ws + OFF_M1F);
    const ushort_t* M2F = (const ushort_t*)(ws + OFF_M2F);

    for (int t = 0; t < T_; t++) {
        const int pr = t & 1;
        float* LPr = ws + (pr ? OFF_LPB : OFF_LP);   // lstm reads
        float* LPw = ws + (pr ? OFF_LP : OFF_LPB);   // lstm writes, pool reads
        ushort_t* HPb = (ushort_t*)(ws + OFF_HP) + pr*524288;

        // ======== L phase (member-local) ========
        ushort_t* atile = (ushort_t*)smem;            // [16][192] bf16 swz (rows 4-15 pad)
        float*    gates = (float*)(smem + 8192);      // [4][512] f32
        float*    h2s   = (float*)(smem + 16384);     // [4][128] f32
        ushort_t* h2b   = (ushort_t*)(smem + 18432);  // [16][128] bf16 swz
        float*    relsh = (float*)(smem + 22528);     // [4][2]

        { const int r = tid >> 6, c = tid & 63;
          atile[(r*192 + c) ^ ((r & 7) << 3)] = (ushort_t)f2b(x_reg); }
        #pragma unroll
        for (int j = 0; j < 2; j++) {
            const int r = 2*(tid >> 7) + j, c = 64 + (tid & 127);
            atile[(r*192 + c) ^ ((r & 7) << 3)] = (ushort_t)f2b(h_reg[j]);
        }
        __syncthreads();

        short8v afr[6];
        #pragma unroll
        for (int kk = 0; kk < 6; kk++)
            afr[kk] = *(const short8v*)&atile[(arow*192 + kk*32 + kch) ^ ((arow & 7) << 3)];

        // gates MFMA: [4rows(pad16)][192] @ [512][192]^T, full N per member
        #pragma unroll 4
        for (int ct = 0; ct < 32; ct++) {
            f32x4 acc = (f32x4){0.f,0.f,0.f,0.f};
            #pragma unroll
            for (int kk = 0; kk < 6; kk++) {
                short8v b = *(const short8v*)&LF[((ct*6 + kk)*64 + lane)*8];
                acc = __builtin_amdgcn_mfma_f32_16x16x32_bf16(afr[kk], b, acc, 0, 0, 0);
            }
            if (lane < 16) {   // C rows 0-3 only (reg = row)
                const int col = ct*16 + lane;
                const float bb = ws[OFF_BG + col];
                #pragma unroll
                for (int reg = 0; reg < 4; reg++)
                    gates[reg*512 + col] = acc[reg] + bb;
            }
        }
        __syncthreads();

        // pointwise (2 items/thread)
        #pragma unroll
        for (int j = 0; j < 2; j++) {
            const int r = 2*(tid >> 7) + j, hc = tid & 127;
            float gi = gates[r*512 + hc];
            float gf = gates[r*512 + 128 + hc];
            float gg = gates[r*512 + 256 + hc];
            float go = gates[r*512 + 384 + hc];
            float c2 = sigf(gf)*c_reg[j] + sigf(gi)*tanhf(gg);
            float h2 = sigf(go)*tanhf(c2);
            c_reg[j] = c2; h_reg[j] = h2;
            h2s[r*128 + hc] = h2;
            h2b[(r*128 + hc) ^ ((r & 7) << 3)] = (ushort_t)f2b(h2);
        }
        __syncthreads();

        // h2p on wave 0: rel = h2 @ Wh2p^T + bh2p; out, LP, relsh
        if (w == 0) {
            const int r = lane >> 4, rr = (lane >> 3) & 1, sub = lane & 7;
            float a = 0.f;
            #pragma unroll 4
            for (int l = 0; l < 16; l++) {
                const int k = sub*16 + l;
                a += h2s[r*128 + k] * ws[F_WH2P + rr*128 + k];
            }
            a += __shfl_xor(a, 1, 64);
            a += __shfl_xor(a, 2, 64);
            a += __shfl_xor(a, 4, 64);
            if (sub == 0) {
                const float rel = a + ws[F_BH2P + rr];
                const int gr = r0 + r;
                out[t*2048 + gr*2 + rr] = rel;
                LPw[gr*2 + rr] = LPr[gr*2 + rr] + rel;
                relsh[r*2 + rr] = rel;
            }
        }
        __syncthreads();

        // X refresh (register)
        x_reg = relsh[(tid >> 6)*2]*wsp0 + relsh[(tid >> 6)*2 + 1]*wsp1 + bsp;

        if (t == T_ - 1) break;

        // hp GEMM: HP[r0..r0+3][512] bf16 = h2 @ Wp1b^T + B512
        {
            short8v hf[4];
            #pragma unroll
            for (int kk = 0; kk < 4; kk++)
                hf[kk] = *(const short8v*)&h2b[(arow*128 + kk*32 + kch) ^ ((arow & 7) << 3)];
            #pragma unroll 4
            for (int ct = 0; ct < 32; ct++) {
                f32x4 acc = (f32x4){0.f,0.f,0.f,0.f};
                #pragma unroll
                for (int kk = 0; kk < 4; kk++) {
                    short8v b = *(const short8v*)&HPF[((ct*4 + kk)*64 + lane)*8];
                    acc = __builtin_amdgcn_mfma_f32_16x16x32_bf16(hf[kk], b, acc, 0, 0, 0);
                }
                if (lane < 16) {
                    const int col = ct*16 + lane;
                    const float bb = ws[OFF_B512 + col];
                    #pragma unroll
                    for (int reg = 0; reg < 4; reg++)
                        HPb[(r0 + reg)*512 + col] = (ushort_t)f2b(acc[reg] + bb);
                }
            }
        }

        group_barrier(cnt, gen);   // scene HP + LP(cur) visible to all 8 members

        // ======== P phase: pool, 4 i's (i = 4m+q) ========
        {
            uint_t* a1b = (uint_t*)smem;               // 32 KB bf16 [32][512] swz
            float*  lpS = (float*)(smem + 32768);      // [32][2]
            const ushort_t* a1u = (const ushort_t*)a1b;
            const float4* A2q = (const float4*)(ws + OFF_A2);
            if (tid < 64) lpS[tid] = LPw[s*64 + tid];
            __syncthreads();

            for (int q = 0; q < 4; q++) {
                const int si = r0 + q;
                const float c0 = lpS[(m*4 + q)*2], c1 = lpS[(m*4 + q)*2 + 1];

                for (int idx = tid; idx < 32*128; idx += 256) {
                    const int jl = idx >> 7, k4 = idx & 127;
                    const float r0p = lpS[jl*2] - c0, r1p = lpS[jl*2 + 1] - c1;
                    uint2 hpv = *(const uint2*)&HPb[(s*32 + jl)*512 + k4*4];
                    float4 a0 = A2q[k4];
                    float4 a1v = A2q[128 + k4];
                    float x = fmaxf(blo(hpv.x) + r0p*a0.x + r1p*a1v.x, 0.f);
                    float y = fmaxf(bhi(hpv.x) + r0p*a0.y + r1p*a1v.y, 0.f);
                    float z = fmaxf(blo(hpv.y) + r0p*a0.z + r1p*a1v.z, 0.f);
                    float w2 = fmaxf(bhi(hpv.y) + r0p*a0.w + r1p*a1v.w, 0.f);
                    const int u = (jl*512 + k4*4) ^ ((jl & 7) << 3);
                    uint2 pk;
                    pk.x = f2b(x) | (f2b(y) << 16);
                    pk.y = f2b(z) | (f2b(w2) << 16);
                    *(uint2*)&a1b[u >> 1] = pk;
                }
                __syncthreads();

                f32x4 acc[2][2];
                #pragma unroll
                for (int jt = 0; jt < 2; jt++)
                    #pragma unroll
                    for (int c = 0; c < 2; c++) acc[jt][c] = (f32x4){0.f,0.f,0.f,0.f};

                #pragma unroll 4
                for (int kk = 0; kk < 16; kk++) {
                    const int kbase = kk*32 + kch;
                    const int ra = arow, rb2 = 16 + arow;
                    short8v a0 = *(const short8v*)&a1u[(ra *512 + kbase) ^ ((ra  & 7) << 3)];
                    short8v a1f= *(const short8v*)&a1u[(rb2*512 + kbase) ^ ((rb2 & 7) << 3)];
                    #pragma unroll
                    for (int c = 0; c < 2; c++) {
                        const int mt = 2*w + c;
                        short8v b = *(const short8v*)&W2F[((mt*16 + kk)*64 + lane)*8];
                        acc[0][c] = __builtin_amdgcn_mfma_f32_16x16x32_bf16(a0,  b, acc[0][c], 0, 0, 0);
                        acc[1][c] = __builtin_amdgcn_mfma_f32_16x16x32_bf16(a1f, b, acc[1][c], 0, 0, 0);
                    }
                }

                float vt[2];
                #pragma unroll
                for (int c = 0; c < 2; c++) {
                    float m0 = fmaxf(fmaxf(acc[0][c][0], acc[0][c][1]), fmaxf(acc[0][c][2], acc[0][c][3]));
                    float m1 = fmaxf(fmaxf(acc[1][c][0], acc[1][c][1]), fmaxf(acc[1][c][2], acc[1][c][3]));
                    float mx = fmaxf(m0, m1);
                    mx = fmaxf(mx, __shfl_xor(mx, 16, 64));
                    mx = fmaxf(mx, __shfl_xor(mx, 32, 64));
                    const int col = (2*w + c)*16 + (lane & 15);
                    vt[c] = fmaxf(mx + ws[F_BP2 + col], 0.f);
                }
                if (lane < 32) {
                    const int tl = lane >> 4;
                    const int col = (2*w + tl)*16 + (lane & 15);
                    ws[OFF_PHP + si*128 + col] = tl ? vt[1] : vt[0];
                }
                __syncthreads();
            }
        }

        // ======== M phase: mlp, 4 rows (member-local) ========
        {
            ushort_t* at    = (ushort_t*)smem;             // [16][256] bf16 swz
            ushort_t* y1    = (ushort_t*)(smem + 8192);    // [16][1024] bf16 swz
            float*    hcout = (float*)(smem + 40960);      // [4][128] f32

            #pragma unroll
            for (int j = 0; j < 2; j++) {
                const int r = 2*(tid >> 7) + j, hc = tid & 127;
                at[(r*256 + hc) ^ ((r & 7) << 3)]       = (ushort_t)f2b(h_reg[j]);
                at[(r*256 + 128 + hc) ^ ((r & 7) << 3)] = (ushort_t)f2b(ws[OFF_PHP + (r0 + r)*128 + hc]);
            }
            __syncthreads();

            short8v af[8];
            #pragma unroll
            for (int kk = 0; kk < 8; kk++)
                af[kk] = *(const short8v*)&at[(arow*256 + kk*32 + kch) ^ ((arow & 7) << 3)];

            #pragma unroll 2
            for (int ct = 0; ct < 64; ct++) {
                f32x4 acc = (f32x4){0.f,0.f,0.f,0.f};
                #pragma unroll
                for (int kk = 0; kk < 8; kk++) {
                    short8v b = *(const short8v*)&M1F[((ct*8 + kk)*64 + lane)*8];
                    acc = __builtin_amdgcn_mfma_f32_16x16x32_bf16(af[kk], b, acc, 0, 0, 0);
                }
                if (lane < 16) {
                    const int col = ct*16 + lane;
                    const float bb = ws[F_BM1 + col];
                    #pragma unroll
                    for (int reg = 0; reg < 4; reg++)
                        y1[(reg*1024 + col) ^ ((reg & 7) << 3)] = (ushort_t)f2b(fmaxf(acc[reg] + bb, 0.f));
                }
            }
            __syncthreads();

            f32x4 acc2[8];
            #pragma unroll
            for (int c = 0; c < 8; c++) acc2[c] = (f32x4){0.f,0.f,0.f,0.f};
            #pragma unroll 4
            for (int kk = 0; kk < 32; kk++) {
                short8v a = *(const short8v*)&y1[(arow*1024 + kk*32 + kch) ^ ((arow & 7) << 3)];
                #pragma unroll
                for (int c = 0; c < 8; c++) {
                    short8v b = *(const short8v*)&M2F[((c*32 + kk)*64 + lane)*8];
                    acc2[c] = __builtin_amdgcn_mfma_f32_16x16x32_bf16(a, b, acc2[c], 0, 0, 0);
                }
            }
            if (lane < 16) {
                #pragma unroll
                for (int c = 0; c < 8; c++) {
                    const int col = c*16 + lane;
                    const float bb = ws[F_BM2 + col];
                    #pragma unroll
                    for (int reg = 0; reg < 4; reg++)
                        hcout[reg*128 + col] = fmaxf(acc2[c][reg] + bb, 0.f);
                }
            }
            __syncthreads();
            #pragma unroll
            for (int j = 0; j < 2; j++)
                h_reg[j] = hcout[(2*(tid >> 7) + j)*128 + (tid & 127)];
            __syncthreads();
        }
    }
}

extern "C" void kernel_launch(void* const* d_in, const int* in_sizes, int n_in,
                              void* d_out, int out_size, void* d_ws, size_t ws_size,
                              hipStream_t stream) {
    float* ws = (float*)d_ws;
    float* out = (float*)d_out;   // reference output dtype is float32

    Ptrs ptrs;   // 22 float tensors, skipping seq_start_end (d_in[4]) and seq_len (d_in[5])
    for (int t = 0; t < 22; t++) ptrs.p[t] = d_in[t < 4 ? t : t + 2];

    k_conv <<<3614, 256, 0, stream>>>(ptrs, ws);   // ceil(925058/256)
    k_init <<<1024, 128, 0, stream>>>(ws);
    k_pre2 <<<2,    256, 0, stream>>>(ws);
    k_packs<<<2432, 256, 0, stream>>>(ws);
    k_run  <<<256,  256, 0, stream>>>(ws, out);
}